// Round 6
// baseline (220.112 us; speedup 1.0000x reference)
//
#include <hip/hip_runtime.h>
#include <hip/hip_bf16.h>

#define C_DIM 1024
#define HEADS 16

typedef __bf16 bf16x8 __attribute__((ext_vector_type(8)));
typedef float f32x4 __attribute__((ext_vector_type(4)));

// round-to-nearest-even f32 -> bf16 (bit pattern)
static __device__ __forceinline__ unsigned short f2bf(float f) {
  unsigned int u = __builtin_bit_cast(unsigned int, f);
  u += 0x7FFFu + ((u >> 16) & 1u);
  return (unsigned short)(u >> 16);
}

static __device__ __forceinline__ __bf16 bits2bf(unsigned short u) {
  return __builtin_bit_cast(__bf16, u);
}

// stage 8 elements (16B of bf16) into LDS, converting f32 on the fly
static __device__ __forceinline__ void stage8(const float* __restrict__ src,
                                              unsigned short* __restrict__ dst) {
  float4 a = *reinterpret_cast<const float4*>(src);
  float4 b = *reinterpret_cast<const float4*>(src + 4);
  ushort4 lo, hi;
  lo.x = f2bf(a.x); lo.y = f2bf(a.y); lo.z = f2bf(a.z); lo.w = f2bf(a.w);
  hi.x = f2bf(b.x); hi.y = f2bf(b.y); hi.z = f2bf(b.z); hi.w = f2bf(b.w);
  *reinterpret_cast<ushort4*>(dst) = lo;
  *reinterpret_cast<ushort4*>(dst + 4) = hi;
}
static __device__ __forceinline__ void stage8(const unsigned short* __restrict__ src,
                                              unsigned short* __restrict__ dst) {
  *reinterpret_cast<ushort4*>(dst) = *reinterpret_cast<const ushort4*>(src);
  *reinterpret_cast<ushort4*>(dst + 4) = *reinterpret_cast<const ushort4*>(src + 4);
}

// ---------------- NT GEMM: C[M][N] = A[M][K] @ B[N][K]^T + bias[N] ----------
// A: f32 or bf16 row-major; B: f32 row-major (weights). 128x128 tile, BK=64,
// 4 waves (2x2), each wave 64x64 = 4x4 frags of mfma_f32_16x16x32_bf16.
// BF16_OUT: write bf16 (ws intermediates) else f32 (d_out).
template <typename TA, bool BF16_OUT>
__global__ __launch_bounds__(256, 2) void gemm_nt(
    const TA* __restrict__ A, const float* __restrict__ B,
    const float* __restrict__ bias, void* __restrict__ Cout,
    int M, int N, int K) {
  __shared__ __align__(16) unsigned short As[128 * 64];
  __shared__ __align__(16) unsigned short Bs[128 * 64];
  const int tid = threadIdx.x;
  const int lane = tid & 63;
  const int wave = tid >> 6;
  const int wm = wave >> 1, wn = wave & 1;
  const int g = lane >> 4, r = lane & 15;
  const int bm = blockIdx.x * 128, bn = blockIdx.y * 128;

  f32x4 acc[4][4] = {};

  for (int k0 = 0; k0 < K; k0 += 64) {
    __syncthreads();
#pragma unroll
    for (int i = 0; i < 4; ++i) {
      int c = i * 256 + tid;        // 1024 chunks of 8 elems per tile
      int row = c >> 3, col = (c & 7) * 8;
      stage8(A + (size_t)(bm + row) * K + k0 + col, &As[row * 64 + col]);
      stage8(B + (size_t)(bn + row) * K + k0 + col, &Bs[row * 64 + col]);
    }
    __syncthreads();

    bf16x8 af[4][2], bf[4][2];
#pragma unroll
    for (int m = 0; m < 4; ++m) {
      af[m][0] = *reinterpret_cast<const bf16x8*>(&As[(wm * 64 + m * 16 + r) * 64 + g * 8]);
      af[m][1] = *reinterpret_cast<const bf16x8*>(&As[(wm * 64 + m * 16 + r) * 64 + 32 + g * 8]);
    }
#pragma unroll
    for (int n = 0; n < 4; ++n) {
      bf[n][0] = *reinterpret_cast<const bf16x8*>(&Bs[(wn * 64 + n * 16 + r) * 64 + g * 8]);
      bf[n][1] = *reinterpret_cast<const bf16x8*>(&Bs[(wn * 64 + n * 16 + r) * 64 + 32 + g * 8]);
    }
#pragma unroll
    for (int m = 0; m < 4; ++m)
#pragma unroll
      for (int n = 0; n < 4; ++n) {
        acc[m][n] = __builtin_amdgcn_mfma_f32_16x16x32_bf16(af[m][0], bf[n][0], acc[m][n], 0, 0, 0);
        acc[m][n] = __builtin_amdgcn_mfma_f32_16x16x32_bf16(af[m][1], bf[n][1], acc[m][n], 0, 0, 0);
      }
  }

  // D layout (m89-verified): row = 4*(lane>>4)+rr, col = lane&15
#pragma unroll
  for (int m = 0; m < 4; ++m) {
    int row0 = bm + wm * 64 + m * 16 + g * 4;
#pragma unroll
    for (int n = 0; n < 4; ++n) {
      int col = bn + wn * 64 + n * 16 + r;
      float bv = bias[col];
#pragma unroll
      for (int rr = 0; rr < 4; ++rr) {
        float v = acc[m][n][rr] + bv;
        if (BF16_OUT)
          reinterpret_cast<unsigned short*>(Cout)[(size_t)(row0 + rr) * N + col] = f2bf(v);
        else
          reinterpret_cast<float*>(Cout)[(size_t)(row0 + rr) * N + col] = v;
      }
    }
  }
}

static __device__ __forceinline__ float bf2f(unsigned short u) {
  unsigned int v = ((unsigned int)u) << 16;
  return __builtin_bit_cast(float, v);
}

// ---------------- LN(q), LN(k), pack Q/K/V to [B][H][N][D] bf16 -------------
// one block per token; qkv row (bf16): q cols [0,1024), k [1024,2048), v rest
__global__ __launch_bounds__(256) void ln_pack_kernel(
    const unsigned short* __restrict__ qkv, const float* __restrict__ qg,
    const float* __restrict__ qb, const float* __restrict__ kg,
    const float* __restrict__ kb, unsigned short* __restrict__ Q,
    unsigned short* __restrict__ Ko, unsigned short* __restrict__ V) {
  const int t = blockIdx.x;
  const int b = t >> 10, n = t & 1023;
  const int tid = threadIdx.x;
  const int lane = tid & 63, wave = tid >> 6;
  const unsigned short* row = qkv + (size_t)t * 3072;
  ushort4 qu = *reinterpret_cast<const ushort4*>(row + tid * 4);
  ushort4 ku = *reinterpret_cast<const ushort4*>(row + 1024 + tid * 4);
  ushort4 vu = *reinterpret_cast<const ushort4*>(row + 2048 + tid * 4);
  float q0 = bf2f(qu.x), q1 = bf2f(qu.y), q2 = bf2f(qu.z), q3 = bf2f(qu.w);
  float k0 = bf2f(ku.x), k1 = bf2f(ku.y), k2 = bf2f(ku.z), k3 = bf2f(ku.w);

  float qs = q0 + q1 + q2 + q3;
  float qss = q0 * q0 + q1 * q1 + q2 * q2 + q3 * q3;
  float ks = k0 + k1 + k2 + k3;
  float kss = k0 * k0 + k1 * k1 + k2 * k2 + k3 * k3;
#pragma unroll
  for (int m = 1; m < 64; m <<= 1) {
    qs += __shfl_xor(qs, m);
    qss += __shfl_xor(qss, m);
    ks += __shfl_xor(ks, m);
    kss += __shfl_xor(kss, m);
  }
  __shared__ float red[4][4];
  if (lane == 0) {
    red[wave][0] = qs; red[wave][1] = qss; red[wave][2] = ks; red[wave][3] = kss;
  }
  __syncthreads();
  qs = red[0][0] + red[1][0] + red[2][0] + red[3][0];
  qss = red[0][1] + red[1][1] + red[2][1] + red[3][1];
  ks = red[0][2] + red[1][2] + red[2][2] + red[3][2];
  kss = red[0][3] + red[1][3] + red[2][3] + red[3][3];
  const float inv = 1.0f / 1024.0f;
  float qmu = qs * inv, kmu = ks * inv;
  float qrs = rsqrtf(qss * inv - qmu * qmu + 1e-5f);
  float krs = rsqrtf(kss * inv - kmu * kmu + 1e-5f);

  int c0 = tid * 4;
  float4 qg4 = *reinterpret_cast<const float4*>(qg + c0);
  float4 qb4 = *reinterpret_cast<const float4*>(qb + c0);
  float4 kg4 = *reinterpret_cast<const float4*>(kg + c0);
  float4 kb4 = *reinterpret_cast<const float4*>(kb + c0);
  int h = c0 >> 6, d = c0 & 63;
  size_t off = (((size_t)(b * HEADS + h)) * 1024 + n) * 64 + d;
  ushort4 qo, ko, vo;
  // fold attention scale D^-0.5 = 1/8 into q
  qo.x = f2bf(((q0 - qmu) * qrs * qg4.x + qb4.x) * 0.125f);
  qo.y = f2bf(((q1 - qmu) * qrs * qg4.y + qb4.y) * 0.125f);
  qo.z = f2bf(((q2 - qmu) * qrs * qg4.z + qb4.z) * 0.125f);
  qo.w = f2bf(((q3 - qmu) * qrs * qg4.w + qb4.w) * 0.125f);
  ko.x = f2bf((k0 - kmu) * krs * kg4.x + kb4.x);
  ko.y = f2bf((k1 - kmu) * krs * kg4.y + kb4.y);
  ko.z = f2bf((k2 - kmu) * krs * kg4.z + kb4.z);
  ko.w = f2bf((k3 - kmu) * krs * kg4.w + kb4.w);
  vo.x = vu.x; vo.y = vu.y; vo.z = vu.z; vo.w = vu.w;  // v passes through
  *reinterpret_cast<ushort4*>(Q + off) = qo;
  *reinterpret_cast<ushort4*>(Ko + off) = ko;
  *reinterpret_cast<ushort4*>(V + off) = vo;
}

// ---------------- flash attention (MFMA) ----------------
// grid.x = B*H, grid.y = 16 (q-blocks of 64). 4 waves; wave handles 16 q rows.
// Q/K/V: [B][H][N=1024][D=64] bf16 (q pre-scaled). Out: [t][h*64+d] bf16.
__global__ __launch_bounds__(256) void attn_kernel(
    const unsigned short* __restrict__ Q, const unsigned short* __restrict__ K,
    const unsigned short* __restrict__ V, unsigned short* __restrict__ O) {
  const int bh = blockIdx.x;
  const int qb = blockIdx.y;
  const int tid = threadIdx.x;
  const int lane = tid & 63, wave = tid >> 6;
  const int g = lane >> 4, r = lane & 15;
  const unsigned short* Qh = Q + (size_t)bh * 1024 * 64;
  const unsigned short* Kh = K + (size_t)bh * 1024 * 64;
  const unsigned short* Vh = V + (size_t)bh * 1024 * 64;
  const int q0 = qb * 64 + wave * 16;

  bf16x8 aq[2];
  aq[0] = *reinterpret_cast<const bf16x8*>(&Qh[(q0 + r) * 64 + g * 8]);
  aq[1] = *reinterpret_cast<const bf16x8*>(&Qh[(q0 + r) * 64 + 32 + g * 8]);

  f32x4 ao[4] = {};
  float mrow[4], lrow[4];
#pragma unroll
  for (int i = 0; i < 4; ++i) { mrow[i] = -1e30f; lrow[i] = 0.f; }

  __shared__ __align__(16) unsigned short Plds[4][16 * 32];
  unsigned short* myP = Plds[wave];

  for (int kt = 0; kt < 1024; kt += 32) {
    // S[16 q][32 keys] = Q @ K^T, two 16-col frags
    f32x4 s[2];
#pragma unroll
    for (int j = 0; j < 2; ++j) {
      bf16x8 bk0 = *reinterpret_cast<const bf16x8*>(&Kh[(kt + j * 16 + r) * 64 + g * 8]);
      bf16x8 bk1 = *reinterpret_cast<const bf16x8*>(&Kh[(kt + j * 16 + r) * 64 + 32 + g * 8]);
      f32x4 t = {};
      t = __builtin_amdgcn_mfma_f32_16x16x32_bf16(aq[0], bk0, t, 0, 0, 0);
      t = __builtin_amdgcn_mfma_f32_16x16x32_bf16(aq[1], bk1, t, 0, 0, 0);
      s[j] = t;
    }
    // online softmax; lane holds rows 4g+rr, col r (per frag)
    float fac[4];
#pragma unroll
    for (int rr = 0; rr < 4; ++rr) {
      float v = fmaxf(s[0][rr], s[1][rr]);
      v = fmaxf(v, __shfl_xor(v, 1));
      v = fmaxf(v, __shfl_xor(v, 2));
      v = fmaxf(v, __shfl_xor(v, 4));
      v = fmaxf(v, __shfl_xor(v, 8));
      float mnew = fmaxf(mrow[rr], v);
      fac[rr] = __expf(mrow[rr] - mnew);
      mrow[rr] = mnew;
      s[0][rr] = __expf(s[0][rr] - mnew);
      s[1][rr] = __expf(s[1][rr] - mnew);
      float ps = s[0][rr] + s[1][rr];
      ps += __shfl_xor(ps, 1);
      ps += __shfl_xor(ps, 2);
      ps += __shfl_xor(ps, 4);
      ps += __shfl_xor(ps, 8);
      lrow[rr] = lrow[rr] * fac[rr] + ps;
    }
#pragma unroll
    for (int n = 0; n < 4; ++n)
#pragma unroll
      for (int rr = 0; rr < 4; ++rr) ao[n][rr] *= fac[rr];

    // P (16x32) -> LDS -> A-frag (lane l: P[l&15][8*(l>>4)+i])
#pragma unroll
    for (int j = 0; j < 2; ++j)
#pragma unroll
      for (int rr = 0; rr < 4; ++rr)
        myP[(4 * g + rr) * 32 + j * 16 + r] = f2bf(s[j][rr]);
    asm volatile("s_waitcnt lgkmcnt(0)" ::: "memory");
    bf16x8 ap = *reinterpret_cast<const bf16x8*>(&myP[r * 32 + g * 8]);

    // O[16][64] += P @ V ; B-frag: V[kt + 8g+i][n*16 + r]
#pragma unroll
    for (int n = 0; n < 4; ++n) {
      bf16x8 bv;
#pragma unroll
      for (int i = 0; i < 8; ++i)
        bv[i] = bits2bf(Vh[(size_t)(kt + g * 8 + i) * 64 + n * 16 + r]);
      ao[n] = __builtin_amdgcn_mfma_f32_16x16x32_bf16(ap, bv, ao[n], 0, 0, 0);
    }
  }

  const int b = bh >> 4, h = bh & 15;
#pragma unroll
  for (int n = 0; n < 4; ++n)
#pragma unroll
    for (int rr = 0; rr < 4; ++rr) {
      int tok = q0 + 4 * g + rr;
      float v = ao[n][rr] / lrow[rr];
      O[(((size_t)(b * 1024 + tok)) * 16 + h) * 64 + n * 16 + r] = f2bf(v);
    }
}

// ---- sentinel: exfiltrate ws_size through absmax --------------------------
__global__ void sentinel_kernel(unsigned short* out, float v) {
  if (threadIdx.x == 0 && blockIdx.x == 0) out[0] = f2bf(v);
}

extern "C" void kernel_launch(void* const* d_in, const int* in_sizes, int n_in,
                              void* d_out, int out_size, void* d_ws, size_t ws_size,
                              hipStream_t stream) {
  const float* x      = (const float*)d_in[0];
  const float* qkv_w  = (const float*)d_in[1];
  const float* qkv_b  = (const float*)d_in[2];
  const float* q_g    = (const float*)d_in[3];
  const float* q_b    = (const float*)d_in[4];
  const float* k_g    = (const float*)d_in[5];
  const float* k_b    = (const float*)d_in[6];
  const float* proj_w = (const float*)d_in[7];
  const float* proj_b = (const float*)d_in[8];

  const int M = in_sizes[0] / C_DIM;  // tokens = B*N
  const int Bb = M / 1024;

  // ws: qkv bf16 [M][3072] | Q/K/V [B][H][N][D] bf16. AO overlays qkv.
  // Total 48 MiB at M=4096 — exactly the round-3-proven bound.
  const size_t required = (size_t)M * 3072 * 2 + (size_t)3 * M * 1024 * 2;
  if (ws_size < required) {
    sentinel_kernel<<<1, 64, 0, stream>>>((unsigned short*)d_out, (float)ws_size);
    return;
  }

  unsigned short* qkv_bf = (unsigned short*)d_ws;               // M*3072
  unsigned short* Qb = qkv_bf + (size_t)M * 3072;
  unsigned short* Kb = Qb + (size_t)M * 1024;
  unsigned short* Vb = Kb + (size_t)M * 1024;
  unsigned short* AO = qkv_bf;                                  // overlay

  gemm_nt<float, true><<<dim3(M / 128, 3072 / 128), 256, 0, stream>>>(
      x, qkv_w, qkv_b, qkv_bf, M, 3072, 1024);

  ln_pack_kernel<<<M, 256, 0, stream>>>(qkv_bf, q_g, q_b, k_g, k_b, Qb, Kb, Vb);

  attn_kernel<<<dim3(Bb * HEADS, 16), 256, 0, stream>>>(Qb, Kb, Vb, AO);

  gemm_nt<unsigned short, false><<<dim3(M / 128, 1024 / 128), 256, 0, stream>>>(
      AO, proj_w, proj_b, (float*)d_out, M, 1024, 1024);
}

// Round 7
// 205.693 us; speedup vs baseline: 1.0701x; 1.0701x over previous
//
#include <hip/hip_runtime.h>
#include <hip/hip_bf16.h>

#define C_DIM 1024
#define HEADS 16

typedef __bf16 bf16x8 __attribute__((ext_vector_type(8)));
typedef float f32x4 __attribute__((ext_vector_type(4)));

// round-to-nearest-even f32 -> bf16 (bit pattern)
static __device__ __forceinline__ unsigned short f2bf(float f) {
  unsigned int u = __builtin_bit_cast(unsigned int, f);
  u += 0x7FFFu + ((u >> 16) & 1u);
  return (unsigned short)(u >> 16);
}

static __device__ __forceinline__ float bf2f(unsigned short u) {
  unsigned int v = ((unsigned int)u) << 16;
  return __builtin_bit_cast(float, v);
}

// async global->LDS 16B (wave-uniform LDS base + lane*16; per-lane global src)
static __device__ __forceinline__ void glds16(const unsigned short* g,
                                              unsigned short* l) {
  __builtin_amdgcn_global_load_lds(
      (const __attribute__((address_space(1))) unsigned int*)g,
      (__attribute__((address_space(3))) unsigned int*)l, 16, 0, 0);
}

// ---------------- cast f32 -> bf16, 4 elems/thread ----------------
__global__ void cast_bf16_kernel(const float* __restrict__ src,
                                 unsigned short* __restrict__ dst, int n4) {
  int i = blockIdx.x * blockDim.x + threadIdx.x;
  if (i >= n4) return;
  float4 v = *reinterpret_cast<const float4*>(src + (size_t)i * 4);
  ushort4 o;
  o.x = f2bf(v.x); o.y = f2bf(v.y); o.z = f2bf(v.z); o.w = f2bf(v.w);
  *reinterpret_cast<ushort4*>(dst + (size_t)i * 4) = o;
}

// ---------------- NT GEMM (m97 structure): C = A @ B^T + bias ----------------
// A,B bf16 row-major. 128x128 tile, BK=64, 4 waves (2x2), 4x4 frags each,
// global_load_lds width-16 staging.
template <bool BF16_OUT>
__global__ __launch_bounds__(256, 2) void gemm_nt(
    const unsigned short* __restrict__ A, const unsigned short* __restrict__ B,
    const float* __restrict__ bias, void* __restrict__ Cout,
    int M, int N, int K) {
  __shared__ __align__(16) unsigned short As[128 * 64];
  __shared__ __align__(16) unsigned short Bs[128 * 64];
  const int tid = threadIdx.x;
  const int lane = tid & 63;
  const int wave = tid >> 6;
  const int wm = wave >> 1, wn = wave & 1;
  const int g = lane >> 4, r = lane & 15;
  const int bm = blockIdx.x * 128, bn = blockIdx.y * 128;

  f32x4 acc[4][4] = {};

  for (int k0 = 0; k0 < K; k0 += 64) {
    __syncthreads();
#pragma unroll
    for (int i = 0; i < 4; ++i) {
      int cb = i * 256 + wave * 64;     // wave-uniform chunk base
      int c = cb + lane;                // 16B chunk index
      int row = c >> 3, col = (c & 7) * 8;
      glds16(&A[(size_t)(bm + row) * K + k0 + col], &As[cb * 8]);
      glds16(&B[(size_t)(bn + row) * K + k0 + col], &Bs[cb * 8]);
    }
    __syncthreads();   // drains vmcnt before frag reads

    bf16x8 af[4][2], bf[4][2];
#pragma unroll
    for (int m = 0; m < 4; ++m) {
      af[m][0] = *reinterpret_cast<const bf16x8*>(&As[(wm * 64 + m * 16 + r) * 64 + g * 8]);
      af[m][1] = *reinterpret_cast<const bf16x8*>(&As[(wm * 64 + m * 16 + r) * 64 + 32 + g * 8]);
    }
#pragma unroll
    for (int n = 0; n < 4; ++n) {
      bf[n][0] = *reinterpret_cast<const bf16x8*>(&Bs[(wn * 64 + n * 16 + r) * 64 + g * 8]);
      bf[n][1] = *reinterpret_cast<const bf16x8*>(&Bs[(wn * 64 + n * 16 + r) * 64 + 32 + g * 8]);
    }
#pragma unroll
    for (int m = 0; m < 4; ++m)
#pragma unroll
      for (int n = 0; n < 4; ++n) {
        acc[m][n] = __builtin_amdgcn_mfma_f32_16x16x32_bf16(af[m][0], bf[n][0], acc[m][n], 0, 0, 0);
        acc[m][n] = __builtin_amdgcn_mfma_f32_16x16x32_bf16(af[m][1], bf[n][1], acc[m][n], 0, 0, 0);
      }
  }

#pragma unroll
  for (int m = 0; m < 4; ++m) {
    int row0 = bm + wm * 64 + m * 16 + g * 4;
#pragma unroll
    for (int n = 0; n < 4; ++n) {
      int col = bn + wn * 64 + n * 16 + r;
      float bv = bias[col];
#pragma unroll
      for (int rr = 0; rr < 4; ++rr) {
        float v = acc[m][n][rr] + bv;
        if (BF16_OUT)
          reinterpret_cast<unsigned short*>(Cout)[(size_t)(row0 + rr) * N + col] = f2bf(v);
        else
          reinterpret_cast<float*>(Cout)[(size_t)(row0 + rr) * N + col] = v;
      }
    }
  }
}

// ---------------- LN(q), LN(k), pack Q/K/V to [B][H][N][D] bf16 -------------
__global__ __launch_bounds__(256) void ln_pack_kernel(
    const unsigned short* __restrict__ qkv, const float* __restrict__ qg,
    const float* __restrict__ qb, const float* __restrict__ kg,
    const float* __restrict__ kb, unsigned short* __restrict__ Q,
    unsigned short* __restrict__ Ko, unsigned short* __restrict__ V) {
  const int t = blockIdx.x;
  const int b = t >> 10, n = t & 1023;
  const int tid = threadIdx.x;
  const int lane = tid & 63, wave = tid >> 6;
  const unsigned short* row = qkv + (size_t)t * 3072;
  ushort4 qu = *reinterpret_cast<const ushort4*>(row + tid * 4);
  ushort4 ku = *reinterpret_cast<const ushort4*>(row + 1024 + tid * 4);
  ushort4 vu = *reinterpret_cast<const ushort4*>(row + 2048 + tid * 4);
  float q0 = bf2f(qu.x), q1 = bf2f(qu.y), q2 = bf2f(qu.z), q3 = bf2f(qu.w);
  float k0 = bf2f(ku.x), k1 = bf2f(ku.y), k2 = bf2f(ku.z), k3 = bf2f(ku.w);

  float qs = q0 + q1 + q2 + q3;
  float qss = q0 * q0 + q1 * q1 + q2 * q2 + q3 * q3;
  float ks = k0 + k1 + k2 + k3;
  float kss = k0 * k0 + k1 * k1 + k2 * k2 + k3 * k3;
#pragma unroll
  for (int m = 1; m < 64; m <<= 1) {
    qs += __shfl_xor(qs, m);
    qss += __shfl_xor(qss, m);
    ks += __shfl_xor(ks, m);
    kss += __shfl_xor(kss, m);
  }
  __shared__ float red[4][4];
  if (lane == 0) {
    red[wave][0] = qs; red[wave][1] = qss; red[wave][2] = ks; red[wave][3] = kss;
  }
  __syncthreads();
  qs = red[0][0] + red[1][0] + red[2][0] + red[3][0];
  qss = red[0][1] + red[1][1] + red[2][1] + red[3][1];
  ks = red[0][2] + red[1][2] + red[2][2] + red[3][2];
  kss = red[0][3] + red[1][3] + red[2][3] + red[3][3];
  const float inv = 1.0f / 1024.0f;
  float qmu = qs * inv, kmu = ks * inv;
  float qrs = rsqrtf(qss * inv - qmu * qmu + 1e-5f);
  float krs = rsqrtf(kss * inv - kmu * kmu + 1e-5f);

  int c0 = tid * 4;
  float4 qg4 = *reinterpret_cast<const float4*>(qg + c0);
  float4 qb4 = *reinterpret_cast<const float4*>(qb + c0);
  float4 kg4 = *reinterpret_cast<const float4*>(kg + c0);
  float4 kb4 = *reinterpret_cast<const float4*>(kb + c0);
  int h = c0 >> 6, d = c0 & 63;
  size_t off = (((size_t)(b * HEADS + h)) * 1024 + n) * 64 + d;
  ushort4 qo, ko, vo;
  // fold attention scale D^-0.5 = 1/8 into q
  qo.x = f2bf(((q0 - qmu) * qrs * qg4.x + qb4.x) * 0.125f);
  qo.y = f2bf(((q1 - qmu) * qrs * qg4.y + qb4.y) * 0.125f);
  qo.z = f2bf(((q2 - qmu) * qrs * qg4.z + qb4.z) * 0.125f);
  qo.w = f2bf(((q3 - qmu) * qrs * qg4.w + qb4.w) * 0.125f);
  ko.x = f2bf((k0 - kmu) * krs * kg4.x + kb4.x);
  ko.y = f2bf((k1 - kmu) * krs * kg4.y + kb4.y);
  ko.z = f2bf((k2 - kmu) * krs * kg4.z + kb4.z);
  ko.w = f2bf((k3 - kmu) * krs * kg4.w + kb4.w);
  vo.x = vu.x; vo.y = vu.y; vo.z = vu.z; vo.w = vu.w;
  *reinterpret_cast<ushort4*>(Q + off) = qo;
  *reinterpret_cast<ushort4*>(Ko + off) = ko;
  *reinterpret_cast<ushort4*>(V + off) = vo;
}

// ---------------- V transpose: [B][H][N][D] -> [B][H][D][N] ----------------
// one block per (bh, 64-token tile); 64x64 bf16 tile through LDS
__global__ __launch_bounds__(256) void transpose_v(
    const unsigned short* __restrict__ V, unsigned short* __restrict__ VT) {
  const int bid = blockIdx.x;
  const int bh = bid >> 4, nt = bid & 15;
  const unsigned short* src = V + (size_t)bh * 65536 + nt * 64 * 64;
  unsigned short* dst = VT + (size_t)bh * 65536 + nt * 64;
  __shared__ __align__(16) unsigned short tile[64][68];
  const int tid = threadIdx.x;
#pragma unroll
  for (int i = 0; i < 4; ++i) {
    int idx = i * 256 + tid;            // 1024 = 64 rows x 16 chunks
    int row = idx >> 4, c4 = (idx & 15) * 4;
    *reinterpret_cast<ushort4*>(&tile[row][c4]) =
        *reinterpret_cast<const ushort4*>(&src[row * 64 + c4]);
  }
  __syncthreads();
#pragma unroll
  for (int i = 0; i < 4; ++i) {
    int idx = i * 256 + tid;
    int d = idx >> 4, n4 = (idx & 15) * 4;
    ushort4 o;
    o.x = tile[n4][d]; o.y = tile[n4 + 1][d];
    o.z = tile[n4 + 2][d]; o.w = tile[n4 + 3][d];
    *reinterpret_cast<ushort4*>(&dst[(size_t)d * 1024 + n4]) = o;
  }
}

// ---------------- flash attention (MFMA, V^T + key-permuted S cols) --------
// grid.x = B*H, grid.y = 16 (q-blocks of 64). 4 waves; wave = 16 q rows.
// Q/K: [B][H][N][D] bf16 (q pre-scaled); VT: [B][H][D][N] bf16.
// S col (j*16+r) holds key kt+2r+j  (permutation-invariant softmax); the
// packed P storage pos p then holds key kt+p = V's natural k-order.
__global__ __launch_bounds__(256) void attn_kernel(
    const unsigned short* __restrict__ Q, const unsigned short* __restrict__ K,
    const unsigned short* __restrict__ VT, unsigned short* __restrict__ O) {
  const int bh = blockIdx.x;
  const int qb = blockIdx.y;
  const int tid = threadIdx.x;
  const int lane = tid & 63, wave = tid >> 6;
  const int g = lane >> 4, r = lane & 15;
  const unsigned short* Qh = Q + (size_t)bh * 65536;
  const unsigned short* Kh = K + (size_t)bh * 65536;
  const unsigned short* Vth = VT + (size_t)bh * 65536;
  const int q0 = qb * 64 + wave * 16;

  bf16x8 aq[2];
  aq[0] = *reinterpret_cast<const bf16x8*>(&Qh[(q0 + r) * 64 + g * 8]);
  aq[1] = *reinterpret_cast<const bf16x8*>(&Qh[(q0 + r) * 64 + 32 + g * 8]);

  f32x4 ao[4] = {};
  float mrow[4], lrow[4];
#pragma unroll
  for (int i = 0; i < 4; ++i) { mrow[i] = -1e30f; lrow[i] = 0.f; }

  // P rows padded to 40 shorts (80B): write 2-way-conflict-free, 16B-aligned
  __shared__ __align__(16) unsigned short Plds[4][16 * 40];
  unsigned short* myP = Plds[wave];

  const unsigned short* kp0 = Kh + (size_t)(2 * r) * 64;  // keys 2r, 2r+1
  const unsigned short* vb0 = Vth + (size_t)r * 1024;     // d-col r (+16n)

  for (int kt = 0; kt < 1024; kt += 32) {
    // S: frag0 = keys kt+2r, frag1 = keys kt+2r+1
    const unsigned short* kp = kp0 + (size_t)kt * 64;
    bf16x8 bk00 = *reinterpret_cast<const bf16x8*>(kp + g * 8);
    bf16x8 bk01 = *reinterpret_cast<const bf16x8*>(kp + 32 + g * 8);
    bf16x8 bk10 = *reinterpret_cast<const bf16x8*>(kp + 64 + g * 8);
    bf16x8 bk11 = *reinterpret_cast<const bf16x8*>(kp + 96 + g * 8);
    f32x4 s0 = {}, s1 = {};
    s0 = __builtin_amdgcn_mfma_f32_16x16x32_bf16(aq[0], bk00, s0, 0, 0, 0);
    s0 = __builtin_amdgcn_mfma_f32_16x16x32_bf16(aq[1], bk01, s0, 0, 0, 0);
    s1 = __builtin_amdgcn_mfma_f32_16x16x32_bf16(aq[0], bk10, s1, 0, 0, 0);
    s1 = __builtin_amdgcn_mfma_f32_16x16x32_bf16(aq[1], bk11, s1, 0, 0, 0);

    // online softmax; lane holds rows 4g+rr, keys (kt+2r, kt+2r+1)
    float fac[4];
#pragma unroll
    for (int rr = 0; rr < 4; ++rr) {
      float v = fmaxf(s0[rr], s1[rr]);
      v = fmaxf(v, __shfl_xor(v, 1));
      v = fmaxf(v, __shfl_xor(v, 2));
      v = fmaxf(v, __shfl_xor(v, 4));
      v = fmaxf(v, __shfl_xor(v, 8));
      float mnew = fmaxf(mrow[rr], v);
      fac[rr] = __expf(mrow[rr] - mnew);
      mrow[rr] = mnew;
      s0[rr] = __expf(s0[rr] - mnew);
      s1[rr] = __expf(s1[rr] - mnew);
      float ps = s0[rr] + s1[rr];
      ps += __shfl_xor(ps, 1);
      ps += __shfl_xor(ps, 2);
      ps += __shfl_xor(ps, 4);
      ps += __shfl_xor(ps, 8);
      lrow[rr] = lrow[rr] * fac[rr] + ps;
    }
#pragma unroll
    for (int n = 0; n < 4; ++n)
#pragma unroll
      for (int rr = 0; rr < 4; ++rr) ao[n][rr] *= fac[rr];

    // P -> LDS: one cvt_pk + one ds_write_b32 per rr (keys 2r,2r+1 adjacent)
#pragma unroll
    for (int rr = 0; rr < 4; ++rr) {
      unsigned int pk;
      asm("v_cvt_pk_bf16_f32 %0, %1, %2" : "=v"(pk) : "v"(s0[rr]), "v"(s1[rr]));
      *reinterpret_cast<unsigned int*>(&myP[(4 * g + rr) * 40 + 2 * r]) = pk;
    }
    asm volatile("s_waitcnt lgkmcnt(0)" ::: "memory");
    bf16x8 ap = *reinterpret_cast<const bf16x8*>(&myP[r * 40 + g * 8]);

    // O += P @ V via V^T: contiguous bf16x8 along keys
    __builtin_amdgcn_s_setprio(1);
#pragma unroll
    for (int n = 0; n < 4; ++n) {
      bf16x8 bv = *reinterpret_cast<const bf16x8*>(vb0 + (size_t)n * 16384 + kt + g * 8);
      ao[n] = __builtin_amdgcn_mfma_f32_16x16x32_bf16(ap, bv, ao[n], 0, 0, 0);
    }
    __builtin_amdgcn_s_setprio(0);
  }

  const int b = bh >> 4, h = bh & 15;
#pragma unroll
  for (int n = 0; n < 4; ++n)
#pragma unroll
    for (int rr = 0; rr < 4; ++rr) {
      int tok = q0 + 4 * g + rr;
      float v = ao[n][rr] / lrow[rr];
      O[(((size_t)(b * 1024 + tok)) * 16 + h) * 64 + n * 16 + r] = f2bf(v);
    }
}

// ---- sentinel: exfiltrate ws_size through absmax --------------------------
__global__ void sentinel_kernel(unsigned short* out, float v) {
  if (threadIdx.x == 0 && blockIdx.x == 0) out[0] = f2bf(v);
}

extern "C" void kernel_launch(void* const* d_in, const int* in_sizes, int n_in,
                              void* d_out, int out_size, void* d_ws, size_t ws_size,
                              hipStream_t stream) {
  const float* x      = (const float*)d_in[0];
  const float* qkv_w  = (const float*)d_in[1];
  const float* qkv_b  = (const float*)d_in[2];
  const float* q_g    = (const float*)d_in[3];
  const float* q_b    = (const float*)d_in[4];
  const float* k_g    = (const float*)d_in[5];
  const float* k_b    = (const float*)d_in[6];
  const float* proj_w = (const float*)d_in[7];
  const float* proj_b = (const float*)d_in[8];

  const int M = in_sizes[0] / C_DIM;  // tokens = B*N
  const int Bb = M / 1024;

  // ws = region A (qkv_bf, M*3072 shorts) + region B (Q/K/V, 3*M*1024 shorts)
  // Total 48 MiB at M=4096 (round-3-proven). Overlays:
  //  pre-GEMM:  x_bf -> Qb slot, qw_bf -> Kb slot (dead after qkv GEMM)
  //  post-ln:   AO -> A+0, VT -> A+M*1024, pw_bf -> A+2*M*1024
  const size_t required = (size_t)M * 3072 * 2 + (size_t)3 * M * 1024 * 2;
  if (ws_size < required) {
    sentinel_kernel<<<1, 64, 0, stream>>>((unsigned short*)d_out, (float)ws_size);
    return;
  }

  unsigned short* qkv_bf = (unsigned short*)d_ws;               // region A
  unsigned short* Qb = qkv_bf + (size_t)M * 3072;               // region B
  unsigned short* Kb = Qb + (size_t)M * 1024;
  unsigned short* Vb = Kb + (size_t)M * 1024;
  unsigned short* x_bf = Qb;                                    // overlay
  unsigned short* qw_bf = Kb;                                   // overlay (3M<=4M)
  unsigned short* AO = qkv_bf;                                  // overlay
  unsigned short* VT = qkv_bf + (size_t)M * 1024;               // overlay
  unsigned short* pw_bf = qkv_bf + (size_t)2 * M * 1024;        // overlay

  cast_bf16_kernel<<<M * 1024 / 1024, 256, 0, stream>>>(x, x_bf, M * 1024 / 4);
  cast_bf16_kernel<<<3072 * 1024 / 1024, 256, 0, stream>>>(qkv_w, qw_bf, 3072 * 1024 / 4);

  gemm_nt<true><<<dim3(M / 128, 3072 / 128), 256, 0, stream>>>(
      x_bf, qw_bf, qkv_b, qkv_bf, M, 3072, 1024);

  ln_pack_kernel<<<M, 256, 0, stream>>>(qkv_bf, q_g, q_b, k_g, k_b, Qb, Kb, Vb);

  transpose_v<<<Bb * HEADS * 16, 256, 0, stream>>>(Vb, VT);
  cast_bf16_kernel<<<1024 * 1024 / 1024, 256, 0, stream>>>(proj_w, pw_bf, 1024 * 1024 / 4);

  attn_kernel<<<dim3(Bb * HEADS, 16), 256, 0, stream>>>(Qb, Kb, VT, AO);

  gemm_nt<false><<<dim3(M / 128, 1024 / 128), 256, 0, stream>>>(
      AO, pw_bf, proj_b, (float*)d_out, M, 1024, 1024);
}